// Round 1
// baseline (327.531 us; speedup 1.0000x reference)
//
#include <hip/hip_runtime.h>

// Problem constants (fixed by setup_inputs: T=8, N=2048, D=256)
#define T_ALL 8
#define T1    7
#define NPTS  2048
#define DD    256
#define BM    32          // rows of src per block
#define BN    128         // cols (dst rows) per chunk
#define BK    32          // k-tile
#define NCHUNK (NPTS / BN)  // 16
#define NKC    (DD / BK)    // 8

// ---------------------------------------------------------------------------
// Kernel 1: normalize descriptors row-wise: x / max(||x||, 1e-8)
// One wave (64 lanes) per row of 256 floats; float4 per lane.
// ---------------------------------------------------------------------------
__global__ __launch_bounds__(256) void norm_kernel(const float* __restrict__ desc,
                                                   float* __restrict__ out) {
    int gid  = blockIdx.x * blockDim.x + threadIdx.x;
    int row  = gid >> 6;          // 0 .. T_ALL*NPTS-1 (grid sized exactly)
    int lane = gid & 63;

    const float4 v = reinterpret_cast<const float4*>(desc)[(size_t)row * (DD / 4) + lane];
    float s = v.x * v.x + v.y * v.y + v.z * v.z + v.w * v.w;
#pragma unroll
    for (int off = 32; off >= 1; off >>= 1)
        s += __shfl_xor(s, off, 64);
    float n = fmaxf(sqrtf(s), 1e-8f);
    float4 o = make_float4(v.x / n, v.y / n, v.z / n, v.w / n);
    reinterpret_cast<float4*>(out)[(size_t)row * (DD / 4) + lane] = o;
}

// ---------------------------------------------------------------------------
// Kernel 2: fused  C = S · Dst^T  +  row-wise max/argmax  +  point gather.
// Block = 256 threads, owns BM=32 src rows for one t.
// sT: full 32x256 S tile, k-major + XOR swizzle (conflict-free b128 reads).
// dT: streamed 32k x 128col Dst tile, k-major + XOR swizzle.
// Each thread: 4 rows x 4 cols register micro-tile.
// ---------------------------------------------------------------------------
__global__ __launch_bounds__(256) void match_kernel(const float* __restrict__ nd,
                                                    const float* __restrict__ pts,
                                                    float* __restrict__ out) {
    __shared__ float sT[DD][BM];        // 32 KB, loc(k,row) = sT[k][row ^ swz(k)]
    __shared__ float dT[BK][BN];        // 16 KB, loc(k,col) = dT[k][col ^ swz(k)]
    __shared__ float redV[BM][33];      // padded: final cross-thread reduce
    __shared__ int   redI[BM][33];

    const int t   = blockIdx.x / (NPTS / BM);
    const int rb  = blockIdx.x % (NPTS / BM);
    const int tid = threadIdx.x;
    const int tm  = tid & 7;            // row group: rows tm*4 .. tm*4+3
    const int tn  = tid >> 3;           // col group: cols tn*4 .. tn*4+3 (0..31)

    const float* S   = nd + ((size_t)t * NPTS + (size_t)rb * BM) * DD;
    const float* Dst = nd + ((size_t)(t + 1) * NPTS) * DD;

    // ---- stage S once: 32 rows x 256 k, transposed into sT with swizzle ----
#pragma unroll
    for (int i = 0; i < 8; ++i) {
        int f   = tid + i * 256;        // float4 index over 32x64
        int row = f >> 6;               // 0..31
        int k4  = f & 63;               // 0..63 (float4 along k)
        float4 v = *reinterpret_cast<const float4*>(S + (size_t)row * DD + k4 * 4);
        int swz = (k4 & 7) << 2;        // swz(k) = ((k>>2)&7)<<2, same for 4 elems
        sT[k4 * 4 + 0][row ^ swz] = v.x;
        sT[k4 * 4 + 1][row ^ swz] = v.y;
        sT[k4 * 4 + 2][row ^ swz] = v.z;
        sT[k4 * 4 + 3][row ^ swz] = v.w;
    }

    float bestV[4];
    int   bestI[4];
#pragma unroll
    for (int r = 0; r < 4; ++r) { bestV[r] = -3.0e38f; bestI[r] = 0; }

    for (int ch = 0; ch < NCHUNK; ++ch) {
        const int col0 = ch * BN;
        float acc[4][4];
#pragma unroll
        for (int r = 0; r < 4; ++r)
#pragma unroll
            for (int c = 0; c < 4; ++c) acc[r][c] = 0.0f;

        for (int kc = 0; kc < NKC; ++kc) {
            __syncthreads();            // protect dT reuse (and sT writes, first pass)
            // ---- stage dT: 128 cols x 32 k, transposed + swizzled ----
#pragma unroll
            for (int i = 0; i < 4; ++i) {
                int f   = tid + i * 256;
                int col = f >> 3;       // 0..127
                int k4  = f & 7;        // 0..7
                float4 v = *reinterpret_cast<const float4*>(
                    Dst + (size_t)(col0 + col) * DD + kc * BK + k4 * 4);
                int swz = k4 << 2;
                dT[k4 * 4 + 0][col ^ swz] = v.x;
                dT[k4 * 4 + 1][col ^ swz] = v.y;
                dT[k4 * 4 + 2][col ^ swz] = v.z;
                dT[k4 * 4 + 3][col ^ swz] = v.w;
            }
            __syncthreads();

#pragma unroll
            for (int kk = 0; kk < BK; ++kk) {
                const int kg   = kc * BK + kk;
                const int swzk = ((kg >> 2) & 7) << 2;
                const int swzd = ((kk >> 2) & 7) << 2;
                float4 a = *reinterpret_cast<const float4*>(&sT[kg][(tm * 4) ^ swzk]);
                float4 b = *reinterpret_cast<const float4*>(&dT[kk][(tn * 4) ^ swzd]);
                float av[4] = {a.x, a.y, a.z, a.w};
                float bv[4] = {b.x, b.y, b.z, b.w};
#pragma unroll
                for (int r = 0; r < 4; ++r)
#pragma unroll
                    for (int c = 0; c < 4; ++c)
                        acc[r][c] = fmaf(av[r], bv[c], acc[r][c]);
            }
        }

        // ---- fold this chunk into the running per-thread (val, idx) max ----
#pragma unroll
        for (int c = 0; c < 4; ++c) {
            int col = col0 + tn * 4 + c;   // ascending within thread -> '>' keeps first
#pragma unroll
            for (int r = 0; r < 4; ++r) {
                if (acc[r][c] > bestV[r]) { bestV[r] = acc[r][c]; bestI[r] = col; }
            }
        }
    }

    // ---- cross-thread reduction: 32 partials per row ----
    __syncthreads();
#pragma unroll
    for (int r = 0; r < 4; ++r) {
        redV[tm * 4 + r][tn] = bestV[r];
        redI[tm * 4 + r][tn] = bestI[r];
    }
    __syncthreads();

    if (tid < BM) {
        float bv = redV[tid][0];
        int   bi = redI[tid][0];
#pragma unroll 8
        for (int j = 1; j < 32; ++j) {
            float v  = redV[tid][j];
            int   ix = redI[tid][j];
            // min-idx tie-break == jnp.argmax first-occurrence semantics
            if (v > bv || (v == bv && ix < bi)) { bv = v; bi = ix; }
        }
        int grow = rb * BM + tid;
        // confidence: starts after matched (T1*NPTS*2 floats)
        out[(size_t)T1 * NPTS * 2 + (size_t)t * NPTS + grow] = bv;
        // matched = points[t+1, argmax, :]
        const float* p = pts + ((size_t)(t + 1) * NPTS + bi) * 2;
        out[((size_t)t * NPTS + grow) * 2 + 0] = p[0];
        out[((size_t)t * NPTS + grow) * 2 + 1] = p[1];
    }
}

// ---------------------------------------------------------------------------
extern "C" void kernel_launch(void* const* d_in, const int* in_sizes, int n_in,
                              void* d_out, int out_size, void* d_ws, size_t ws_size,
                              hipStream_t stream) {
    const float* desc = (const float*)d_in[0];   // [8, 2048, 256] fp32
    const float* pts  = (const float*)d_in[1];   // [8, 2048, 2]   fp32
    float* nd = (float*)d_ws;                    // normalized copy, 16 MB

    // 16384 rows, one wave each, 4 waves/block
    norm_kernel<<<(T_ALL * NPTS) / 4, 256, 0, stream>>>(desc, nd);
    // 7 * 64 row-blocks
    match_kernel<<<T1 * (NPTS / BM), 256, 0, stream>>>(nd, pts, (float*)d_out);
}

// Round 2
// 227.421 us; speedup vs baseline: 1.4402x; 1.4402x over previous
//
#include <hip/hip_runtime.h>

// Problem constants (fixed by setup_inputs: T=8, N=2048, D=256)
#define T_ALL 8
#define T1    7
#define NPTS  2048
#define DD    256
#define BM    32            // src rows per block
#define BN    128           // dst cols per LDS tile
#define BK    32            // k-tile
#define SPLIT 4             // column split factor (parallelism)
#define COLS_PER_SPLIT (NPTS / SPLIT)        // 512
#define NCH   (COLS_PER_SPLIT / BN)          // 4 chunks per block
#define NKC   (DD / BK)                      // 8
#define NROUND (NCH * NKC)                   // 32 staging rounds

// ws layout (floats): [0,16M) nd ; partV at NDF; partI after
#define NDF   (T_ALL * NPTS * DD)            // 4194304 floats
#define NPART (T1 * SPLIT * NPTS)            // 57344

// ---------------------------------------------------------------------------
// Kernel 1: normalize descriptors row-wise: x / max(||x||, 1e-8)
// ---------------------------------------------------------------------------
__global__ __launch_bounds__(256) void norm_kernel(const float* __restrict__ desc,
                                                   float* __restrict__ out) {
    int gid  = blockIdx.x * blockDim.x + threadIdx.x;
    int row  = gid >> 6;
    int lane = gid & 63;

    const float4 v = reinterpret_cast<const float4*>(desc)[(size_t)row * (DD / 4) + lane];
    float s = v.x * v.x + v.y * v.y + v.z * v.z + v.w * v.w;
#pragma unroll
    for (int off = 32; off >= 1; off >>= 1)
        s += __shfl_xor(s, off, 64);
    float n = fmaxf(sqrtf(s), 1e-8f);
    float4 o = make_float4(v.x / n, v.y / n, v.z / n, v.w / n);
    reinterpret_cast<float4*>(out)[(size_t)row * (DD / 4) + lane] = o;
}

// ---------------------------------------------------------------------------
// Kernel 2: partial fused GEMM + row max/argmax over a 512-col split.
// Block: 256 threads, 32 src rows, cols [sp*512, sp*512+512).
// sT: 32x256 S tile (k-major, write-swizzled). dT: 32k x 128col streamed tile.
// Per-thread 4x4 micro-tile. Register prefetch of next dT round (T14).
// ---------------------------------------------------------------------------
__global__ __launch_bounds__(256) void match_kernel(const float* __restrict__ nd,
                                                    float* __restrict__ partV,
                                                    int* __restrict__ partI) {
    __shared__ float sT[DD][BM];        // 32 KB : elem(k,row) at sT[k][row ^ (((k>>2)&7)<<2)]
    __shared__ float dT[BK][BN];        // 16 KB : elem(k,col) at dT[k][col ^ ((k>>2)<<2)]
    float* redV = &dT[0][0];            // alias, 4 KB (32x32)
    int*   redI = (int*)&dT[8][0];      // alias, 4 KB

    const int bid = blockIdx.x;
    const int sp  = bid & (SPLIT - 1);
    const int rb  = (bid >> 2) & 63;
    const int t   = bid >> 8;
    const int tid = threadIdx.x;
    const int tm4 = (tid & 7) << 2;     // row offset
    const int tn  = tid >> 3;           // 0..31
    const int tn4 = tn << 2;            // col offset in tile

    const float* S   = nd + ((size_t)t * NPTS + (size_t)rb * BM) * DD;
    const float* Dst = nd + ((size_t)(t + 1) * NPTS + sp * COLS_PER_SPLIT) * DD;

    // ---- stage S once (32 rows x 256 k, transposed + write-swizzled) ----
#pragma unroll
    for (int i = 0; i < 8; ++i) {
        int f   = tid + i * 256;
        int row = f >> 6;               // 0..31
        int k4  = f & 63;               // float4 index along k
        float4 v = *reinterpret_cast<const float4*>(S + (size_t)row * DD + k4 * 4);
        int swz = (k4 & 7) << 2;
        sT[k4 * 4 + 0][row ^ swz] = v.x;
        sT[k4 * 4 + 1][row ^ swz] = v.y;
        sT[k4 * 4 + 2][row ^ swz] = v.z;
        sT[k4 * 4 + 3][row ^ swz] = v.w;
    }

    // ---- dT staging geometry (per thread, fixed): k4 = tid&7, col = tid>>3 + 32i
    const int sk4  = tid & 7;
    const int scol = tid >> 3;

    // prologue: prefetch round 0
    float4 pr[4];
#pragma unroll
    for (int i = 0; i < 4; ++i)
        pr[i] = *reinterpret_cast<const float4*>(
            Dst + (size_t)(scol + 32 * i) * DD + sk4 * 4);

    float bestV[4];
    int   bestI[4];
    float acc[4][4];
#pragma unroll
    for (int r = 0; r < 4; ++r) { bestV[r] = -3.0e38f; bestI[r] = 0; }
#pragma unroll
    for (int r = 0; r < 4; ++r)
#pragma unroll
        for (int c = 0; c < 4; ++c) acc[r][c] = 0.0f;

    for (int g = 0; g < NROUND; ++g) {
        const int kc = g & 7;
        __syncthreads();                 // dT free (previous compute done); covers sT on g=0
        {
            const int swz = sk4 << 2;
#pragma unroll
            for (int i = 0; i < 4; ++i) {
                int col = scol + 32 * i;
                dT[sk4 * 4 + 0][col ^ swz] = pr[i].x;
                dT[sk4 * 4 + 1][col ^ swz] = pr[i].y;
                dT[sk4 * 4 + 2][col ^ swz] = pr[i].z;
                dT[sk4 * 4 + 3][col ^ swz] = pr[i].w;
            }
        }
        if (g + 1 < NROUND) {            // issue next round's loads; wait lands after compute
            const int ch2 = (g + 1) >> 3;
            const int kc2 = (g + 1) & 7;
#pragma unroll
            for (int i = 0; i < 4; ++i)
                pr[i] = *reinterpret_cast<const float4*>(
                    Dst + (size_t)(ch2 * BN + scol + 32 * i) * DD + kc2 * BK + sk4 * 4);
        }
        __syncthreads();                 // dT ready

#pragma unroll
        for (int kk = 0; kk < BK; ++kk) {
            const int swzc = (kk >> 2) << 2;        // compile-time per kk
            float4 a = *reinterpret_cast<const float4*>(&sT[kc * BK + kk][tm4 ^ swzc]);
            float4 b = *reinterpret_cast<const float4*>(&dT[kk][tn4 ^ swzc]);
            float av[4] = {a.x, a.y, a.z, a.w};
            float bv[4] = {b.x, b.y, b.z, b.w};
#pragma unroll
            for (int r = 0; r < 4; ++r)
#pragma unroll
                for (int c = 0; c < 4; ++c)
                    acc[r][c] = fmaf(av[r], bv[c], acc[r][c]);
        }

        if ((g & 7) == 7) {              // chunk finished: fold into running max
            const int col0 = sp * COLS_PER_SPLIT + (g >> 3) * BN + tn4;
#pragma unroll
            for (int c = 0; c < 4; ++c) {
                int col = col0 + c;      // ascending -> '>' keeps first occurrence
#pragma unroll
                for (int r = 0; r < 4; ++r) {
                    if (acc[r][c] > bestV[r]) { bestV[r] = acc[r][c]; bestI[r] = col; }
                }
            }
#pragma unroll
            for (int r = 0; r < 4; ++r)
#pragma unroll
                for (int c = 0; c < 4; ++c) acc[r][c] = 0.0f;
        }
    }

    // ---- cross-thread reduction: 32 partials per row (alias dT) ----
    __syncthreads();
#pragma unroll
    for (int r = 0; r < 4; ++r) {
        redV[tn * 32 + (tm4 + r)] = bestV[r];
        redI[tn * 32 + (tm4 + r)] = bestI[r];
    }
    __syncthreads();

    if (tid < BM) {
        float bv = redV[tid];
        int   bi = redI[tid];
#pragma unroll 8
        for (int j = 1; j < 32; ++j) {
            float v  = redV[j * 32 + tid];
            int   ix = redI[j * 32 + tid];
            if (v > bv || (v == bv && ix < bi)) { bv = v; bi = ix; }
        }
        int idx = ((t * SPLIT + sp) << 11) + rb * BM + tid;
        partV[idx] = bv;
        partI[idx] = bi;
    }
}

// ---------------------------------------------------------------------------
// Kernel 3: merge the 4 split-partials per row, gather points, write output.
// ---------------------------------------------------------------------------
__global__ __launch_bounds__(256) void reduce_kernel(const float* __restrict__ partV,
                                                     const int* __restrict__ partI,
                                                     const float* __restrict__ pts,
                                                     float* __restrict__ out) {
    int r = blockIdx.x * 256 + threadIdx.x;     // 0 .. T1*NPTS-1
    int t   = r >> 11;
    int row = r & (NPTS - 1);

    float bv = -3.0e38f;
    int   bi = 0;
#pragma unroll
    for (int sp = 0; sp < SPLIT; ++sp) {
        int idx = ((t * SPLIT + sp) << 11) + row;
        float v  = partV[idx];
        int   ix = partI[idx];
        if (v > bv || (v == bv && ix < bi)) { bv = v; bi = ix; }
    }
    out[(size_t)T1 * NPTS * 2 + r] = bv;
    const float* p = pts + ((size_t)(t + 1) * NPTS + bi) * 2;
    out[(size_t)r * 2 + 0] = p[0];
    out[(size_t)r * 2 + 1] = p[1];
}

// ---------------------------------------------------------------------------
extern "C" void kernel_launch(void* const* d_in, const int* in_sizes, int n_in,
                              void* d_out, int out_size, void* d_ws, size_t ws_size,
                              hipStream_t stream) {
    const float* desc = (const float*)d_in[0];   // [8, 2048, 256] fp32
    const float* pts  = (const float*)d_in[1];   // [8, 2048, 2]   fp32
    float* nd    = (float*)d_ws;                 // 16 MB normalized copy
    float* partV = nd + NDF;
    int*   partI = (int*)(nd + NDF + NPART);

    norm_kernel<<<(T_ALL * NPTS) / 4, 256, 0, stream>>>(desc, nd);
    match_kernel<<<T1 * 64 * SPLIT, 256, 0, stream>>>(nd, partV, partI);
    reduce_kernel<<<(T1 * NPTS) / 256, 256, 0, stream>>>(partV, partI, pts, (float*)d_out);
}